// Round 8
// baseline (2884.890 us; speedup 1.0000x reference)
//
#include <hip/hip_runtime.h>
#include <hip/hip_bf16.h>

typedef __bf16 bf16x8 __attribute__((ext_vector_type(8)));
typedef float f32x4 __attribute__((ext_vector_type(4)));
typedef unsigned uint4v __attribute__((ext_vector_type(4)));
typedef unsigned long long u64;

constexpr int Bb = 128, Tt = 512, Ff = 64, Hh = 512, Gg = 2048;
constexpr int K0 = Hh + 64;   // 576  = [h | x]
constexpr int K1 = Hh + Hh;   // 1024 = [h1 | h0]
constexpr int NITER = Tt + 1; // 513

// ws offsets (16B-aligned). h planes store PACKED u32 = bf16_hi | bf16_lo<<16
// (value = hi + lo, ~17 mantissa bits; exchanged via system-scope (IF$) ops).
constexpr size_t OFF_W0  = 0;                                   // bf16 [2048][576]  [w_hh_0 | w_ih_0]
constexpr size_t OFF_W1  = OFF_W0 + (size_t)Gg * K0 * 2;        // bf16 [2048][1024] [w_hh_1 | w_ih_1]
constexpr size_t OFF_B0  = OFF_W1 + (size_t)Gg * K1 * 2;        // f32 [2048]
constexpr size_t OFF_B1  = OFF_B0 + (size_t)Gg * 4;
constexpr size_t OFF_HI0 = OFF_B1 + (size_t)Gg * 4;             // u32 [2][128][512] (dbuf parity)
constexpr size_t OFF_HI1 = OFF_HI0 + (size_t)2 * Bb * Hh * 4;   // u32 [2][128][512]
constexpr size_t OFF_HF  = OFF_HI1 + (size_t)2 * Bb * Hh * 4;   // f32 [128][512] final h1
constexpr size_t OFF_FLG = OFF_HF + (size_t)Bb * Hh * 4;        // u32 [513][2][8][32] split flags
// total ~9.5 MiB

__global__ void prep(const float* __restrict__ wih0, const float* __restrict__ whh0,
                     const float* __restrict__ bih0, const float* __restrict__ bhh0,
                     const float* __restrict__ wih1, const float* __restrict__ whh1,
                     const float* __restrict__ bih1, const float* __restrict__ bhh1,
                     unsigned char* __restrict__ ws)
{
  __hip_bfloat16* W0 = reinterpret_cast<__hip_bfloat16*>(ws + OFF_W0);
  __hip_bfloat16* W1 = reinterpret_cast<__hip_bfloat16*>(ws + OFF_W1);
  float* B0 = reinterpret_cast<float*>(ws + OFF_B0);
  float* B1 = reinterpret_cast<float*>(ws + OFF_B1);
  unsigned* HI0 = reinterpret_cast<unsigned*>(ws + OFF_HI0);
  unsigned* HI1 = reinterpret_cast<unsigned*>(ws + OFF_HI1);
  unsigned* FLG = reinterpret_cast<unsigned*>(ws + OFF_FLG);

  const size_t tid = (size_t)blockIdx.x * blockDim.x + threadIdx.x;
  const size_t stp = (size_t)gridDim.x * blockDim.x;

  for (size_t i = tid; i < (size_t)Gg * K0; i += stp) {
    int g = (int)(i / K0), k = (int)(i % K0);
    float v = (k < Hh) ? whh0[(size_t)g * Hh + k] : wih0[(size_t)g * 64 + (k - Hh)];
    W0[i] = __float2bfloat16(v);
  }
  for (size_t i = tid; i < (size_t)Gg * K1; i += stp) {
    int g = (int)(i / K1), k = (int)(i % K1);
    float v = (k < Hh) ? whh1[(size_t)g * Hh + k] : wih1[(size_t)g * Hh + (k - Hh)];
    W1[i] = __float2bfloat16(v);
  }
  for (size_t i = tid; i < (size_t)Gg; i += stp) {
    B0[i] = bih0[i] + bhh0[i];
    B1[i] = bih1[i] + bhh1[i];
  }
  // zero h planes (both parities; packed 0 == (0,0)) and ALL barrier flags
  for (size_t i = tid; i < (size_t)2 * Bb * Hh; i += stp) { HI0[i] = 0u; HI1[i] = 0u; }
  for (size_t i = tid; i < (size_t)NITER * 512; i += stp) FLG[i] = 0u;
}

__device__ __forceinline__ float sigf(float x)   { return 1.f / (1.f + __expf(-x)); }
__device__ __forceinline__ float tanhf_(float x) { return 1.f - 2.f / (1.f + __expf(2.f * x)); }

// pack value as bf16 hi|lo<<16 (RNE both)
__device__ __forceinline__ unsigned pack_hl(float v) {
  __bf16 hb = (__bf16)v;
  __bf16 lb = (__bf16)(v - (float)hb);
  return (unsigned)__builtin_bit_cast(unsigned short, hb)
       | ((unsigned)__builtin_bit_cast(unsigned short, lb) << 16);
}

// Read 8 packed u32 (k..k+7) for row fr from a swizzled LDS slab; unpack to
// hi/lo bf16x8. Swizzle col ^= (row&7)<<2 (u32 units, 16B granularity).
__device__ __forceinline__ void lds_frag(const unsigned* sh, int fr, int cb,
                                         bf16x8& hi, bf16x8& lo) {
  const int sw = (fr & 7) << 2;
  const unsigned* row = sh + fr * Hh;
  uint4v qa = *reinterpret_cast<const uint4v*>(row + (cb ^ sw));
  uint4v qb = *reinterpret_cast<const uint4v*>(row + ((cb + 4) ^ sw));
  uint4v hw = { __builtin_amdgcn_perm(qa[1], qa[0], 0x05040100u),
                __builtin_amdgcn_perm(qa[3], qa[2], 0x05040100u),
                __builtin_amdgcn_perm(qb[1], qb[0], 0x05040100u),
                __builtin_amdgcn_perm(qb[3], qb[2], 0x05040100u) };
  uint4v lw = { __builtin_amdgcn_perm(qa[1], qa[0], 0x07060302u),
                __builtin_amdgcn_perm(qa[3], qa[2], 0x07060302u),
                __builtin_amdgcn_perm(qb[1], qb[0], 0x07060302u),
                __builtin_amdgcn_perm(qb[3], qb[2], 0x07060302u) };
  hi = __builtin_bit_cast(bf16x8, hw);
  lo = __builtin_bit_cast(bf16x8, lw);
}

// Poll 32 per-WG flags in parallel (wave 0), then release the block.
__device__ __forceinline__ void wait_flags(const unsigned* base, int lane, int w4) {
  if (w4 == 0 && lane < 32) {
    while (__hip_atomic_load(base + lane, __ATOMIC_RELAXED, __HIP_MEMORY_SCOPE_SYSTEM) == 0u) {}
  }
  asm volatile("" ::: "memory");
  __syncthreads();
}

// Drain this block's publish stores to the IF$ coherence point, then set flag.
__device__ __forceinline__ void set_flag(unsigned* slot, int hs) {
  asm volatile("s_waitcnt vmcnt(0)" ::: "memory");  // per-wave drain
  __syncthreads();                                   // all waves drained
  if (threadIdx.x == 0)
    __hip_atomic_store(slot, 1u, __ATOMIC_RELAXED, __HIP_MEMORY_SCOPE_SYSTEM);
}

// 256 WGs x 256 threads, 1 WG/CU. WG = (batch-group gb: 16 rows) x (hidden
// slice hs: 16 units); 4 waves K-split. SPLIT-PHASE pipeline: flag0[t] (h0(t)
// ready) set mid-iteration, flag1[t] set at iteration end; each layer's
// exchange round-trip hides under the other layer's compute phase.
__global__ __launch_bounds__(256, 1)
void lstm_main(const __hip_bfloat16* __restrict__ W0, const __hip_bfloat16* __restrict__ W1,
               const float* __restrict__ B0, const float* __restrict__ B1,
               unsigned* __restrict__ HI0, unsigned* __restrict__ HI1,
               float* __restrict__ HF, unsigned* __restrict__ FLG,
               const float* __restrict__ xg,
               const float* __restrict__ linw, const float* __restrict__ linb,
               float* __restrict__ out)
{
  const int tid  = threadIdx.x;
  const int lane = tid & 63;
  const int w4   = tid >> 6;          // wave id 0..3 (K-split)
  const int gb   = blockIdx.x & 7;    // batch group
  const int hs   = blockIdx.x >> 3;   // hidden slice 0..31
  const int b0   = gb << 4;
  const int j0   = hs << 4;
  const int fr   = lane & 15;         // frag row (A batch-row / B gate-row)
  const int fk   = (lane >> 4) << 3;  // frag k offset within 32-k slice

  __shared__ unsigned sh0[16 * Hh];   // h0(t-1) slab (swizzled)
  __shared__ unsigned sh1[16 * Hh];   // h1(t-2) slab (swizzled)
  __shared__ float p0[4][4][16][20];
  __shared__ float p1[4][4][16][20];

  // layer-0 K split: 18 slices of 32 over 4 waves = {5,5,4,4}
  const int ks0 = (w4 < 2) ? w4 * 5 : 10 + (w4 - 2) * 4;
  const int kc0 = (w4 < 2) ? 5 : 4;

  // --- register-resident weight fragments (single bf16; pinned) ---
  bf16x8 wf0[4][5], wf1[4][8];
  #pragma unroll
  for (int g = 0; g < 4; ++g) {
    const size_t rw0 = (size_t)(g * Hh + j0 + fr) * K0;
    const size_t rw1 = (size_t)(g * Hh + j0 + fr) * K1;
    #pragma unroll
    for (int s = 0; s < 5; ++s) {
      int ks = ks0 + ((s < kc0) ? s : 0);   // clamp: unused slot replicates
      wf0[g][s] = *reinterpret_cast<const bf16x8*>(W0 + rw0 + ks * 32 + fk);
    }
    #pragma unroll
    for (int s = 0; s < 8; ++s)
      wf1[g][s] = *reinterpret_cast<const bf16x8*>(W1 + rw1 + (w4 * 8 + s) * 32 + fk);
  }
  #pragma unroll
  for (int g = 0; g < 4; ++g) {
    #pragma unroll
    for (int s = 0; s < 5; ++s) asm volatile("" : "+v"(wf0[g][s]));
    #pragma unroll
    for (int s = 0; s < 8; ++s) asm volatile("" : "+v"(wf1[g][s]));
  }

  const int um = tid >> 4, uj = tid & 15;
  float bs0[4], bs1[4];
  #pragma unroll
  for (int g = 0; g < 4; ++g) {
    bs0[g] = B0[g * Hh + j0 + uj];
    bs1[g] = B1[g * Hh + j0 + uj];
  }
  float c0 = 0.f, c1 = 0.f;

  // iteration it: layer0 computes t=it (it<512); layer1 computes t'=it-1 (it>=1)
  for (int it = 0; it <= Tt; ++it) {
    const int p = it & 1;
    const size_t rdo = (size_t)p * (Bb * Hh), wro = (size_t)(p ^ 1) * (Bb * Hh);

    // ---- 1: hoist x fragments (wave 3 owns K-slices 16,17) — VALU while polling ----
    bf16x8 axh0{}, axl0{}, axh1{}, axl1{};
    if (w4 == 3 && it < Tt) {
      const float* xr = xg + ((size_t)(b0 + fr) * Tt + it) * 64 + fk;
      #pragma unroll
      for (int s2 = 0; s2 < 2; ++s2) {
        f32x4 v0 = *reinterpret_cast<const f32x4*>(xr + s2 * 32);
        f32x4 v1 = *reinterpret_cast<const f32x4*>(xr + s2 * 32 + 4);
        bf16x8 hh, ll;
        #pragma unroll
        for (int j = 0; j < 4; ++j) {
          float v = v0[j];  __bf16 hb = (__bf16)v;
          hh[j] = hb;  ll[j] = (__bf16)(v - (float)hb);
          v = v1[j];  hb = (__bf16)v;
          hh[j + 4] = hb;  ll[j + 4] = (__bf16)(v - (float)hb);
        }
        if (s2 == 0) { axh0 = hh; axl0 = ll; } else { axh1 = hh; axl1 = ll; }
      }
    }

    // ---- 2-5: waits + slab load issue (h0 first — it's the critical chain) ----
    if (it >= 1)
      wait_flags(FLG + ((size_t)(it - 1) * 2 + 0) * 256 + gb * 32, lane, w4);
    u64 ld0[16];
    #pragma unroll
    for (int k = 0; k < 16; ++k)
      ld0[k] = __hip_atomic_load(
          reinterpret_cast<const u64*>(HI0 + rdo + (size_t)(b0 + k) * Hh) + tid,
          __ATOMIC_RELAXED, __HIP_MEMORY_SCOPE_SYSTEM);
    if (it >= 2)
      wait_flags(FLG + ((size_t)(it - 2) * 2 + 1) * 256 + gb * 32, lane, w4);
    u64 ld1[16];
    #pragma unroll
    for (int k = 0; k < 16; ++k)
      ld1[k] = __hip_atomic_load(
          reinterpret_cast<const u64*>(HI1 + rdo + (size_t)(b0 + k) * Hh) + tid,
          __ATOMIC_RELAXED, __HIP_MEMORY_SCOPE_SYSTEM);

    // ---- 6: stage sh0, release ----
    #pragma unroll
    for (int k = 0; k < 16; ++k)
      *reinterpret_cast<u64*>(sh0 + k * Hh + ((tid * 2) ^ ((k & 7) << 2))) = ld0[k];
    __syncthreads();

    // ---- 7: layer-0 MFMA (A = hi+lo -> 2 MFMAs/slice) ----
    if (it < Tt) {
      bf16x8 ah[5], al[5];
      #pragma unroll
      for (int s = 0; s < 5; ++s) {
        const int ks = ks0 + ((s < kc0) ? s : 0);
        const int k0 = ks * 32;
        if (k0 < Hh) {
          lds_frag(sh0, fr, k0 + fk, ah[s], al[s]);
        } else {                       // wave 3, slices 16/17: hoisted x frags
          ah[s] = (ks == 16) ? axh0 : axh1;
          al[s] = (ks == 16) ? axl0 : axl1;
        }
      }
      f32x4 acc[4] = {};
      #pragma unroll
      for (int s = 0; s < 5; ++s) {
        if (s < kc0) {
          #pragma unroll
          for (int g = 0; g < 4; ++g) {
            acc[g] = __builtin_amdgcn_mfma_f32_16x16x32_bf16(ah[s], wf0[g][s], acc[g], 0, 0, 0);
            acc[g] = __builtin_amdgcn_mfma_f32_16x16x32_bf16(al[s], wf0[g][s], acc[g], 0, 0, 0);
          }
        }
      }
      #pragma unroll
      for (int g = 0; g < 4; ++g)
        *reinterpret_cast<f32x4*>(&p0[w4][g][fr][(lane >> 4) << 2]) = acc[g];
    }
    __syncthreads();                   // p0 ready

    // ---- 9+10: L0 update + publish h0(t); sh1 staging hides under this VALU ----
    #pragma unroll
    for (int k = 0; k < 16; ++k)
      *reinterpret_cast<u64*>(sh1 + k * Hh + ((tid * 2) ^ ((k & 7) << 2))) = ld1[k];
    if (it < Tt) {
      float gv[4];
      #pragma unroll
      for (int g = 0; g < 4; ++g)
        gv[g] = p0[0][g][uj][um] + p0[1][g][uj][um] + p0[2][g][uj][um] + p0[3][g][uj][um] + bs0[g];
      float iv = sigf(gv[0]), fv = sigf(gv[1]), gg = tanhf_(gv[2]), ov = sigf(gv[3]);
      c0 = fv * c0 + iv * gg;
      float hv = ov * tanhf_(c0);
      __hip_atomic_store(HI0 + wro + (size_t)(b0 + um) * Hh + j0 + uj, pack_hl(hv),
                         __ATOMIC_RELAXED, __HIP_MEMORY_SCOPE_SYSTEM);
      // ---- 11: drain + flag0[it]; internal sync also releases sh1 writes ----
      set_flag(FLG + ((size_t)it * 2 + 0) * 256 + gb * 32 + hs, hs);
    } else {
      __syncthreads();                 // release sh1 at it==Tt
    }

    // ---- 12: layer-1 MFMA (waves 0-1: sh1; waves 2-3: sh0) ----
    if (it >= 1) {
      f32x4 acc[4] = {};
      #pragma unroll
      for (int s = 0; s < 8; ++s) {
        const int k0 = (w4 * 8 + s) * 32;
        bf16x8 ah, al;
        if (k0 < Hh) lds_frag(sh1, fr, k0 + fk, ah, al);
        else         lds_frag(sh0, fr, (k0 - Hh) + fk, ah, al);
        #pragma unroll
        for (int g = 0; g < 4; ++g) {
          acc[g] = __builtin_amdgcn_mfma_f32_16x16x32_bf16(ah, wf1[g][s], acc[g], 0, 0, 0);
          acc[g] = __builtin_amdgcn_mfma_f32_16x16x32_bf16(al, wf1[g][s], acc[g], 0, 0, 0);
        }
      }
      #pragma unroll
      for (int g = 0; g < 4; ++g)
        *reinterpret_cast<f32x4*>(&p1[w4][g][fr][(lane >> 4) << 2]) = acc[g];
    }
    __syncthreads();                   // p1 ready; also guards sh0/sh1 rewrite next iter

    // ---- 14+15: L1 update + publish h1(it-1) + flag1[it-1] ----
    if (it >= 1) {
      float gv[4];
      #pragma unroll
      for (int g = 0; g < 4; ++g)
        gv[g] = p1[0][g][uj][um] + p1[1][g][uj][um] + p1[2][g][uj][um] + p1[3][g][uj][um] + bs1[g];
      float iv = sigf(gv[0]), fv = sigf(gv[1]), gg = tanhf_(gv[2]), ov = sigf(gv[3]);
      c1 = fv * c1 + iv * gg;
      float hv = ov * tanhf_(c1);
      __hip_atomic_store(HI1 + wro + (size_t)(b0 + um) * Hh + j0 + uj, pack_hl(hv),
                         __ATOMIC_RELAXED, __HIP_MEMORY_SCOPE_SYSTEM);
      if (it == Tt)
        __hip_atomic_store(HF + (size_t)(b0 + um) * Hh + j0 + uj, hv,
                           __ATOMIC_RELAXED, __HIP_MEMORY_SCOPE_SYSTEM);
      set_flag(FLG + ((size_t)(it - 1) * 2 + 1) * 256 + gb * 32 + hs, hs);
    }
  }

  // ---- TERMINAL SYNC (round-7 bug fix): epilogue reads HF tiles written by
  // ALL 32 WGs of the group — wait for every WG's flag1[Tt-1] (set after its
  // vmcnt(0)-drained HF stores) before touching HF. Missing this wait made
  // the graph-replay revalidation fail intermittently.
  wait_flags(FLG + ((size_t)(Tt - 1) * 2 + 1) * 256 + gb * 32, lane, w4);

  // ---- epilogue (in-group): block (gb, hs<16) -> out[gb*16 + hs], fp32 exact ----
  if (hs < 16 && tid < 64) {
    const int b = (gb << 4) + hs;
    float s = 0.f;
    #pragma unroll
    for (int i = 0; i < 8; ++i) {
      int j = i * 64 + tid;
      float hv = __hip_atomic_load(HF + (size_t)b * Hh + j, __ATOMIC_RELAXED,
                                   __HIP_MEMORY_SCOPE_SYSTEM);
      s += hv * linw[j];
    }
    #pragma unroll
    for (int off = 32; off >= 1; off >>= 1) s += __shfl_down(s, off, 64);
    if (tid == 0) out[b] = s + linb[0];
  }
}

extern "C" void kernel_launch(void* const* d_in, const int* in_sizes, int n_in,
                              void* d_out, int out_size, void* d_ws, size_t ws_size,
                              hipStream_t stream)
{
  const float* x    = (const float*)d_in[0];
  const float* wih0 = (const float*)d_in[1];
  const float* whh0 = (const float*)d_in[2];
  const float* bih0 = (const float*)d_in[3];
  const float* bhh0 = (const float*)d_in[4];
  const float* wih1 = (const float*)d_in[5];
  const float* whh1 = (const float*)d_in[6];
  const float* bih1 = (const float*)d_in[7];
  const float* bhh1 = (const float*)d_in[8];
  const float* linw = (const float*)d_in[9];
  const float* linb = (const float*)d_in[10];
  float* outp = (float*)d_out;
  unsigned char* ws = (unsigned char*)d_ws;

  prep<<<256, 256, 0, stream>>>(wih0, whh0, bih0, bhh0, wih1, whh1, bih1, bhh1, ws);

  lstm_main<<<256, 256, 0, stream>>>(
      (const __hip_bfloat16*)(ws + OFF_W0), (const __hip_bfloat16*)(ws + OFF_W1),
      (const float*)(ws + OFF_B0), (const float*)(ws + OFF_B1),
      (unsigned*)(ws + OFF_HI0), (unsigned*)(ws + OFF_HI1),
      (float*)(ws + OFF_HF), (unsigned*)(ws + OFF_FLG),
      x, linw, linb, outp);
}

// Round 9
// 2873.128 us; speedup vs baseline: 1.0041x; 1.0041x over previous
//
#include <hip/hip_runtime.h>
#include <hip/hip_bf16.h>

typedef __bf16 bf16x8 __attribute__((ext_vector_type(8)));
typedef float f32x4 __attribute__((ext_vector_type(4)));
typedef unsigned uint4v __attribute__((ext_vector_type(4)));
typedef unsigned long long u64;

constexpr int Bb = 128, Tt = 512, Ff = 64, Hh = 512, Gg = 2048;
constexpr int K0 = Hh + 64;   // 576  = [h | x]
constexpr int K1 = Hh + Hh;   // 1024 = [h1 | h0]
constexpr int NITER = Tt + 1; // 513

// ws offsets (16B-aligned). h planes store PACKED u32 = bf16_hi | bf16_lo<<16
// (value = hi + lo, ~17 mantissa bits). Exchange transport: WIDE plain loads/
// stores with sc0 sc1 (IF$ coherence point, wave-coalesced) — NOT per-lane
// atomics (round-8 lesson: atomics gave 20x request amplification, 323 MB/iter).
constexpr size_t OFF_W0  = 0;                                   // bf16 [2048][576]  [w_hh_0 | w_ih_0]
constexpr size_t OFF_W1  = OFF_W0 + (size_t)Gg * K0 * 2;        // bf16 [2048][1024] [w_hh_1 | w_ih_1]
constexpr size_t OFF_B0  = OFF_W1 + (size_t)Gg * K1 * 2;        // f32 [2048]
constexpr size_t OFF_B1  = OFF_B0 + (size_t)Gg * 4;
constexpr size_t OFF_HI0 = OFF_B1 + (size_t)Gg * 4;             // u32 [2][128][512] (dbuf parity)
constexpr size_t OFF_HI1 = OFF_HI0 + (size_t)2 * Bb * Hh * 4;   // u32 [2][128][512]
constexpr size_t OFF_HF  = OFF_HI1 + (size_t)2 * Bb * Hh * 4;   // f32 [128][512] final h1
constexpr size_t OFF_FLG = OFF_HF + (size_t)Bb * Hh * 4;        // u32 [513][2][8][32] split flags
// total ~9.5 MiB

__global__ void prep(const float* __restrict__ wih0, const float* __restrict__ whh0,
                     const float* __restrict__ bih0, const float* __restrict__ bhh0,
                     const float* __restrict__ wih1, const float* __restrict__ whh1,
                     const float* __restrict__ bih1, const float* __restrict__ bhh1,
                     unsigned char* __restrict__ ws)
{
  __hip_bfloat16* W0 = reinterpret_cast<__hip_bfloat16*>(ws + OFF_W0);
  __hip_bfloat16* W1 = reinterpret_cast<__hip_bfloat16*>(ws + OFF_W1);
  float* B0 = reinterpret_cast<float*>(ws + OFF_B0);
  float* B1 = reinterpret_cast<float*>(ws + OFF_B1);
  unsigned* HI0 = reinterpret_cast<unsigned*>(ws + OFF_HI0);
  unsigned* HI1 = reinterpret_cast<unsigned*>(ws + OFF_HI1);
  unsigned* FLG = reinterpret_cast<unsigned*>(ws + OFF_FLG);

  const size_t tid = (size_t)blockIdx.x * blockDim.x + threadIdx.x;
  const size_t stp = (size_t)gridDim.x * blockDim.x;

  for (size_t i = tid; i < (size_t)Gg * K0; i += stp) {
    int g = (int)(i / K0), k = (int)(i % K0);
    float v = (k < Hh) ? whh0[(size_t)g * Hh + k] : wih0[(size_t)g * 64 + (k - Hh)];
    W0[i] = __float2bfloat16(v);
  }
  for (size_t i = tid; i < (size_t)Gg * K1; i += stp) {
    int g = (int)(i / K1), k = (int)(i % K1);
    float v = (k < Hh) ? whh1[(size_t)g * Hh + k] : wih1[(size_t)g * Hh + (k - Hh)];
    W1[i] = __float2bfloat16(v);
  }
  for (size_t i = tid; i < (size_t)Gg; i += stp) {
    B0[i] = bih0[i] + bhh0[i];
    B1[i] = bih1[i] + bhh1[i];
  }
  // zero h planes (both parities) and ALL flags. prep's plain stores are
  // published to IF$/HBM by the end-of-kernel L2 flush -> visible to sc1 reads.
  for (size_t i = tid; i < (size_t)2 * Bb * Hh; i += stp) { HI0[i] = 0u; HI1[i] = 0u; }
  for (size_t i = tid; i < (size_t)NITER * 512; i += stp) FLG[i] = 0u;
}

__device__ __forceinline__ float sigf(float x)   { return 1.f / (1.f + __expf(-x)); }
__device__ __forceinline__ float tanhf_(float x) { return 1.f - 2.f / (1.f + __expf(2.f * x)); }

// pack value as bf16 hi|lo<<16 (RNE both)
__device__ __forceinline__ unsigned pack_hl(float v) {
  __bf16 hb = (__bf16)v;
  __bf16 lb = (__bf16)(v - (float)hb);
  return (unsigned)__builtin_bit_cast(unsigned short, hb)
       | ((unsigned)__builtin_bit_cast(unsigned short, lb) << 16);
}

// ---- IF$-coherent wide transport (plain ops, sc0|sc1 = bypass L1+L2) ----
__device__ __forceinline__ uint4v load16_sys(const unsigned* p) {
  uint4v r;
  asm volatile("global_load_dwordx4 %0, %1, off sc0 sc1" : "=&v"(r) : "v"(p));
  return r;
}
__device__ __forceinline__ void storeu32_sys(unsigned* p, unsigned v) {
  asm volatile("global_store_dword %0, %1, off sc0 sc1" :: "v"(p), "v"(v) : "memory");
}
__device__ __forceinline__ void storef32_sys(float* p, float v) {
  asm volatile("global_store_dword %0, %1, off sc0 sc1" :: "v"(p), "v"(v) : "memory");
}

// Read 8 packed u32 (k..k+7) for row fr from a swizzled LDS slab; unpack to
// hi/lo bf16x8. Swizzle col ^= (row&7)<<2 (u32 units, 16B granularity).
__device__ __forceinline__ void lds_frag(const unsigned* sh, int fr, int cb,
                                         bf16x8& hi, bf16x8& lo) {
  const int sw = (fr & 7) << 2;
  const unsigned* row = sh + fr * Hh;
  uint4v qa = *reinterpret_cast<const uint4v*>(row + (cb ^ sw));
  uint4v qb = *reinterpret_cast<const uint4v*>(row + ((cb + 4) ^ sw));
  uint4v hw = { __builtin_amdgcn_perm(qa[1], qa[0], 0x05040100u),
                __builtin_amdgcn_perm(qa[3], qa[2], 0x05040100u),
                __builtin_amdgcn_perm(qb[1], qb[0], 0x05040100u),
                __builtin_amdgcn_perm(qb[3], qb[2], 0x05040100u) };
  uint4v lw = { __builtin_amdgcn_perm(qa[1], qa[0], 0x07060302u),
                __builtin_amdgcn_perm(qa[3], qa[2], 0x07060302u),
                __builtin_amdgcn_perm(qb[1], qb[0], 0x07060302u),
                __builtin_amdgcn_perm(qb[3], qb[2], 0x07060302u) };
  hi = __builtin_bit_cast(bf16x8, hw);
  lo = __builtin_bit_cast(bf16x8, lw);
}

// Poll the group's 32 flags with 8 lanes x dwordx4 (8 requests/poll, latency-
// throttled by the in-asm vmcnt) instead of 32 per-lane atomics.
__device__ __forceinline__ void wait_flags(const unsigned* base, int lane, int w4) {
  if (w4 == 0 && lane < 8) {
    const unsigned* p = base + lane * 4;
    while (true) {
      uint4v f;
      asm volatile("global_load_dwordx4 %0, %1, off sc0 sc1\n\t"
                   "s_waitcnt vmcnt(0)"
                   : "=&v"(f) : "v"(p) : "memory");
      if ((f[0] & f[1] & f[2] & f[3]) != 0u) break;
    }
  }
  __syncthreads();
}

// Drain this block's sc1 publish stores to the IF$ coherence point, then flag.
__device__ __forceinline__ void set_flag(unsigned* slot, int hs) {
  asm volatile("s_waitcnt vmcnt(0)" ::: "memory");  // per-wave drain (covers asm stores)
  __syncthreads();                                   // all waves drained
  if (threadIdx.x == 0)
    __hip_atomic_store(slot, 1u, __ATOMIC_RELAXED, __HIP_MEMORY_SCOPE_SYSTEM);
}

// 256 WGs x 256 threads, 1 WG/CU. WG = (batch-group gb: 16 rows) x (hidden
// slice hs: 16 units); 4 waves K-split. Per iter: 16 wide sc1 loads pull both
// 32KB slabs (flat, 16B/thread), stage to swizzled LDS, L0/L1 MFMA phases,
// publish via sc1 stores, split flags (flag0 mid-iter, flag1 at end).
__global__ __launch_bounds__(256, 1)
void lstm_main(const __hip_bfloat16* __restrict__ W0, const __hip_bfloat16* __restrict__ W1,
               const float* __restrict__ B0, const float* __restrict__ B1,
               unsigned* __restrict__ HI0, unsigned* __restrict__ HI1,
               float* __restrict__ HF, unsigned* __restrict__ FLG,
               const float* __restrict__ xg,
               const float* __restrict__ linw, const float* __restrict__ linb,
               float* __restrict__ out)
{
  const int tid  = threadIdx.x;
  const int lane = tid & 63;
  const int w4   = tid >> 6;          // wave id 0..3 (K-split)
  const int gb   = blockIdx.x & 7;    // batch group
  const int hs   = blockIdx.x >> 3;   // hidden slice 0..31
  const int b0   = gb << 4;
  const int j0   = hs << 4;
  const int fr   = lane & 15;         // frag row (A batch-row / B gate-row)
  const int fk   = (lane >> 4) << 3;  // frag k offset within 32-k slice

  __shared__ unsigned sh0[16 * Hh];   // h0(t-1) slab (swizzled)
  __shared__ unsigned sh1[16 * Hh];   // h1(t-2) slab (swizzled)
  __shared__ float p0[4][4][16][20];
  __shared__ float p1[4][4][16][20];

  // layer-0 K split: 18 slices of 32 over 4 waves = {5,5,4,4}
  const int ks0 = (w4 < 2) ? w4 * 5 : 10 + (w4 - 2) * 4;
  const int kc0 = (w4 < 2) ? 5 : 4;

  // --- register-resident weight fragments (single bf16; pinned) ---
  bf16x8 wf0[4][5], wf1[4][8];
  #pragma unroll
  for (int g = 0; g < 4; ++g) {
    const size_t rw0 = (size_t)(g * Hh + j0 + fr) * K0;
    const size_t rw1 = (size_t)(g * Hh + j0 + fr) * K1;
    #pragma unroll
    for (int s = 0; s < 5; ++s) {
      int ks = ks0 + ((s < kc0) ? s : 0);   // clamp: unused slot replicates
      wf0[g][s] = *reinterpret_cast<const bf16x8*>(W0 + rw0 + ks * 32 + fk);
    }
    #pragma unroll
    for (int s = 0; s < 8; ++s)
      wf1[g][s] = *reinterpret_cast<const bf16x8*>(W1 + rw1 + (w4 * 8 + s) * 32 + fk);
  }
  #pragma unroll
  for (int g = 0; g < 4; ++g) {
    #pragma unroll
    for (int s = 0; s < 5; ++s) asm volatile("" : "+v"(wf0[g][s]));
    #pragma unroll
    for (int s = 0; s < 8; ++s) asm volatile("" : "+v"(wf1[g][s]));
  }

  const int um = tid >> 4, uj = tid & 15;
  float bs0[4], bs1[4];
  #pragma unroll
  for (int g = 0; g < 4; ++g) {
    bs0[g] = B0[g * Hh + j0 + uj];
    bs1[g] = B1[g * Hh + j0 + uj];
  }
  float c0 = 0.f, c1 = 0.f;

  // iteration it: layer0 computes t=it (it<512); layer1 computes t'=it-1 (it>=1)
  for (int it = 0; it <= Tt; ++it) {
    const int p = it & 1;
    const size_t rdo = (size_t)p * (Bb * Hh), wro = (size_t)(p ^ 1) * (Bb * Hh);

    // ---- 1: hoist x fragments (wave 3 owns K-slices 16,17) ----
    bf16x8 axh0{}, axl0{}, axh1{}, axl1{};
    if (w4 == 3 && it < Tt) {
      const float* xr = xg + ((size_t)(b0 + fr) * Tt + it) * 64 + fk;
      #pragma unroll
      for (int s2 = 0; s2 < 2; ++s2) {
        f32x4 v0 = *reinterpret_cast<const f32x4*>(xr + s2 * 32);
        f32x4 v1 = *reinterpret_cast<const f32x4*>(xr + s2 * 32 + 4);
        bf16x8 hh, ll;
        #pragma unroll
        for (int j = 0; j < 4; ++j) {
          float v = v0[j];  __bf16 hb = (__bf16)v;
          hh[j] = hb;  ll[j] = (__bf16)(v - (float)hb);
          v = v1[j];  hb = (__bf16)v;
          hh[j + 4] = hb;  ll[j + 4] = (__bf16)(v - (float)hb);
        }
        if (s2 == 0) { axh0 = hh; axl0 = ll; } else { axh1 = hh; axl1 = ll; }
      }
    }

    // ---- 2: waits (flag1 is ~1.5 iters old -> normally already set) ----
    if (it >= 1)
      wait_flags(FLG + ((size_t)(it - 1) * 2 + 0) * 256 + gb * 32, lane, w4);
    if (it >= 2)
      wait_flags(FLG + ((size_t)(it - 2) * 2 + 1) * 256 + gb * 32, lane, w4);

    // ---- 3: slab loads — 16 wide coalesced sc1 loads (16B/thread each) ----
    const unsigned* s0base = HI0 + rdo + (size_t)b0 * Hh;   // 32KB contiguous
    const unsigned* s1base = HI1 + rdo + (size_t)b0 * Hh;
    uint4v ld0[8], ld1[8];
    #pragma unroll
    for (int i = 0; i < 8; ++i) ld0[i] = load16_sys(s0base + i * 1024 + tid * 4);
    #pragma unroll
    for (int i = 0; i < 8; ++i) ld1[i] = load16_sys(s1base + i * 1024 + tid * 4);
    asm volatile("s_waitcnt vmcnt(0)" ::: "memory");

    // ---- 4: stage both slabs to LDS (XOR-swizzled), release ----
    #pragma unroll
    for (int i = 0; i < 8; ++i) {
      const int r = 2 * i + (tid >> 7);
      const int c = (tid & 127) * 4;
      const int cs = c ^ ((r & 7) << 2);
      *reinterpret_cast<uint4v*>(sh0 + r * Hh + cs) = ld0[i];
      *reinterpret_cast<uint4v*>(sh1 + r * Hh + cs) = ld1[i];
    }
    __syncthreads();

    // ---- 5: layer-0 MFMA (A = hi+lo -> 2 MFMAs/slice) ----
    if (it < Tt) {
      bf16x8 ah[5], al[5];
      #pragma unroll
      for (int s = 0; s < 5; ++s) {
        const int ks = ks0 + ((s < kc0) ? s : 0);
        const int k0 = ks * 32;
        if (k0 < Hh) {
          lds_frag(sh0, fr, k0 + fk, ah[s], al[s]);
        } else {                       // wave 3, slices 16/17: hoisted x frags
          ah[s] = (ks == 16) ? axh0 : axh1;
          al[s] = (ks == 16) ? axl0 : axl1;
        }
      }
      f32x4 acc[4] = {};
      #pragma unroll
      for (int s = 0; s < 5; ++s) {
        if (s < kc0) {
          #pragma unroll
          for (int g = 0; g < 4; ++g) {
            acc[g] = __builtin_amdgcn_mfma_f32_16x16x32_bf16(ah[s], wf0[g][s], acc[g], 0, 0, 0);
            acc[g] = __builtin_amdgcn_mfma_f32_16x16x32_bf16(al[s], wf0[g][s], acc[g], 0, 0, 0);
          }
        }
      }
      #pragma unroll
      for (int g = 0; g < 4; ++g)
        *reinterpret_cast<f32x4*>(&p0[w4][g][fr][(lane >> 4) << 2]) = acc[g];
    }
    __syncthreads();                   // p0 ready

    // ---- 6: L0 update + publish h0(t) (sc1 stores) + flag0[it] ----
    if (it < Tt) {
      float gv[4];
      #pragma unroll
      for (int g = 0; g < 4; ++g)
        gv[g] = p0[0][g][uj][um] + p0[1][g][uj][um] + p0[2][g][uj][um] + p0[3][g][uj][um] + bs0[g];
      float iv = sigf(gv[0]), fv = sigf(gv[1]), gg = tanhf_(gv[2]), ov = sigf(gv[3]);
      c0 = fv * c0 + iv * gg;
      float hv = ov * tanhf_(c0);
      storeu32_sys(HI0 + wro + (size_t)(b0 + um) * Hh + j0 + uj, pack_hl(hv));
      set_flag(FLG + ((size_t)it * 2 + 0) * 256 + gb * 32 + hs, hs);
    }

    // ---- 7: layer-1 MFMA (waves 0-1: sh1; waves 2-3: sh0) ----
    if (it >= 1) {
      f32x4 acc[4] = {};
      #pragma unroll
      for (int s = 0; s < 8; ++s) {
        const int k0 = (w4 * 8 + s) * 32;
        bf16x8 ah, al;
        if (k0 < Hh) lds_frag(sh1, fr, k0 + fk, ah, al);
        else         lds_frag(sh0, fr, (k0 - Hh) + fk, ah, al);
        #pragma unroll
        for (int g = 0; g < 4; ++g) {
          acc[g] = __builtin_amdgcn_mfma_f32_16x16x32_bf16(ah, wf1[g][s], acc[g], 0, 0, 0);
          acc[g] = __builtin_amdgcn_mfma_f32_16x16x32_bf16(al, wf1[g][s], acc[g], 0, 0, 0);
        }
      }
      #pragma unroll
      for (int g = 0; g < 4; ++g)
        *reinterpret_cast<f32x4*>(&p1[w4][g][fr][(lane >> 4) << 2]) = acc[g];
    }
    __syncthreads();                   // p1 ready; also guards sh0/sh1 rewrite next iter

    // ---- 8: L1 update + publish h1(it-1) (sc1) + flag1[it-1] ----
    if (it >= 1) {
      float gv[4];
      #pragma unroll
      for (int g = 0; g < 4; ++g)
        gv[g] = p1[0][g][uj][um] + p1[1][g][uj][um] + p1[2][g][uj][um] + p1[3][g][uj][um] + bs1[g];
      float iv = sigf(gv[0]), fv = sigf(gv[1]), gg = tanhf_(gv[2]), ov = sigf(gv[3]);
      c1 = fv * c1 + iv * gg;
      float hv = ov * tanhf_(c1);
      storeu32_sys(HI1 + wro + (size_t)(b0 + um) * Hh + j0 + uj, pack_hl(hv));
      if (it == Tt)
        storef32_sys(HF + (size_t)(b0 + um) * Hh + j0 + uj, hv);
      set_flag(FLG + ((size_t)(it - 1) * 2 + 1) * 256 + gb * 32 + hs, hs);
    }
  }

  // ---- TERMINAL SYNC: epilogue reads HF written by ALL 32 WGs of the group;
  // wait for every WG's flag1[Tt-1] (set after its drained HF stores).
  wait_flags(FLG + ((size_t)(Tt - 1) * 2 + 1) * 256 + gb * 32, lane, w4);

  // ---- epilogue (in-group): block (gb, hs<16) -> out[gb*16 + hs], fp32 exact ----
  if (hs < 16 && tid < 64) {
    const int b = (gb << 4) + hs;
    float s = 0.f;
    #pragma unroll
    for (int i = 0; i < 8; ++i) {
      int j = i * 64 + tid;
      float hv = __hip_atomic_load(HF + (size_t)b * Hh + j, __ATOMIC_RELAXED,
                                   __HIP_MEMORY_SCOPE_SYSTEM);
      s += hv * linw[j];
    }
    #pragma unroll
    for (int off = 32; off >= 1; off >>= 1) s += __shfl_down(s, off, 64);
    if (tid == 0) out[b] = s + linb[0];
  }
}

extern "C" void kernel_launch(void* const* d_in, const int* in_sizes, int n_in,
                              void* d_out, int out_size, void* d_ws, size_t ws_size,
                              hipStream_t stream)
{
  const float* x    = (const float*)d_in[0];
  const float* wih0 = (const float*)d_in[1];
  const float* whh0 = (const float*)d_in[2];
  const float* bih0 = (const float*)d_in[3];
  const float* bhh0 = (const float*)d_in[4];
  const float* wih1 = (const float*)d_in[5];
  const float* whh1 = (const float*)d_in[6];
  const float* bih1 = (const float*)d_in[7];
  const float* bhh1 = (const float*)d_in[8];
  const float* linw = (const float*)d_in[9];
  const float* linb = (const float*)d_in[10];
  float* outp = (float*)d_out;
  unsigned char* ws = (unsigned char*)d_ws;

  prep<<<256, 256, 0, stream>>>(wih0, whh0, bih0, bhh0, wih1, whh1, bih1, bhh1, ws);

  lstm_main<<<256, 256, 0, stream>>>(
      (const __hip_bfloat16*)(ws + OFF_W0), (const __hip_bfloat16*)(ws + OFF_W1),
      (const float*)(ws + OFF_B0), (const float*)(ws + OFF_B1),
      (unsigned*)(ws + OFF_HI0), (unsigned*)(ws + OFF_HI1),
      (float*)(ws + OFF_HF), (unsigned*)(ws + OFF_FLG),
      x, linw, linb, outp);
}